// Round 19
// baseline (120.227 us; speedup 1.0000x reference)
//
#include <hip/hip_runtime.h>
#include <hip/hip_fp16.h>
#include <math.h>

// HieraFormer fused block:
//   transpose -> MFMA QKV proj -> fused attn (QT=32, 8 waves, cross-wave
//   global_load_lds staging, 2-buffer depth-1 raw-barrier counted-vmcnt
//   pipeline (R16-verified), swapped-MFMA QK^T -> reg-resident fp16 z ->
//   wave-local quadratic Newton -> MFMA PV) -> LN+residual.
// B=2, D_MODEL=384, H=3, D_K=128, N=2048.
#define DM   384
#define NH   3
#define DK   128
#define NSEQ 2048
#define BATCH 2
#define NTOK (BATCH*NSEQ)      // 4096
#define SEG  (BATCH*NSEQ*DM)   // 1572864 elements
#define NEWTON_IT 6
#define QT   32                // q-rows per block (halves K/V L2 traffic vs 16)
#define ZP   520               // z LDS pitch in halves (512 + 8)

typedef __attribute__((ext_vector_type(8))) short     bf16x8;
typedef __attribute__((ext_vector_type(4))) float     f32x4;
typedef __attribute__((ext_vector_type(8))) _Float16  h8;
typedef __attribute__((ext_vector_type(4))) _Float16  h4;
typedef __attribute__((ext_vector_type(2))) _Float16  h2v;

#if __has_builtin(__builtin_amdgcn_fdot2)
#define HAVE_FDOT2 1
#else
#define HAVE_FDOT2 0
#endif

// global -> LDS async DMA, 16B/lane. Global src per-lane; LDS dest wave-uniform
// (HW adds lane*16).
typedef const unsigned int __attribute__((address_space(1)))* gas1_t;
typedef unsigned int __attribute__((address_space(3)))* las3_t;
__device__ __forceinline__ void gll16(const void* g, void* l) {
  __builtin_amdgcn_global_load_lds((gas1_t)g, (las3_t)l, 16, 0, 0);
}

__device__ __forceinline__ unsigned short f2bf(float f) {
  unsigned u = __builtin_bit_cast(unsigned, f);
  u += 0x7FFFu + ((u >> 16) & 1u);          // RNE
  return (unsigned short)(u >> 16);
}

// ---------------------------------------------------------------- transpose
__global__ __launch_bounds__(256) void transpose_k(const float* __restrict__ x,
                                                   float* __restrict__ xT,
                                                   unsigned short* __restrict__ xbf) {
  __shared__ float tile[32][33];
  int b  = blockIdx.z;
  int cB = blockIdx.y * 32;
  int nB = blockIdx.x * 32;
  int tx = threadIdx.x & 31, ty = threadIdx.x >> 5;
#pragma unroll
  for (int i = 0; i < 4; i++)
    tile[ty + i*8][tx] = x[((size_t)b*DM + cB + ty + i*8)*NSEQ + nB + tx];
  __syncthreads();
#pragma unroll
  for (int i = 0; i < 4; i++) {
    float v = tile[tx][ty + i*8];
    size_t row = (size_t)b*NSEQ + nB + ty + i*8;
    xT [row*DM + cB + tx] = v;
    xbf[row*DM + cB + tx] = f2bf(v);
  }
}

// ---------------------------------------------------------------- weight convert
__global__ __launch_bounds__(256) void wconv_k(const float* __restrict__ wq,
    const float* __restrict__ wk, const float* __restrict__ wv,
    unsigned short* __restrict__ wbf) {
  int pj = blockIdx.y;
  const float* src = (pj == 0) ? wq : (pj == 1) ? wk : wv;
  int i = (blockIdx.x * 256 + threadIdx.x) * 4;
  float4 v = *(const float4*)(src + i);
  ushort4 o;
  o.x = f2bf(v.x); o.y = f2bf(v.y); o.z = f2bf(v.z); o.w = f2bf(v.w);
  *(ushort4*)(wbf + (size_t)pj*DM*DM + i) = o;
}

// ---------------------------------------------------------------- MFMA projections
// Q,K -> bf16 [b][h][n][d];  V -> fp16 transposed VT [b][h][d][n].
__global__ __launch_bounds__(256) void proj_mfma_k(
    const unsigned short* __restrict__ xbf,   // [NTOK][DM]
    const unsigned short* __restrict__ wbf,   // [3][DM][DM]
    const float* __restrict__ bq, const float* __restrict__ bk, const float* __restrict__ bv,
    unsigned short* __restrict__ Qo, unsigned short* __restrict__ Ko,
    unsigned short* __restrict__ VTo) {      // VT stored as f16 bit-pattern
  int tid = threadIdx.x, lane = tid & 63, w = tid >> 6;
  int g = lane >> 4, li = lane & 15;
  int wr = w >> 1, wc = w & 1;
  int h  = blockIdx.y;
  int pj = blockIdx.z;
  const unsigned short* wp0 = wbf + (size_t)pj * DM * DM;
  const float* bias = (pj == 0) ? bq : (pj == 1) ? bk : bv;

  const unsigned short *Am, *Bn;
  int mB, nB;
  if (pj < 2) { Am = wp0; mB = h*128 + wr*64;          Bn = xbf; nB = blockIdx.x*128 + wc*64; }
  else        { Am = xbf; mB = blockIdx.x*128 + wr*64; Bn = wp0; nB = h*128 + wc*64; }

  f32x4 acc[4][4];
#pragma unroll
  for (int fi = 0; fi < 4; fi++)
#pragma unroll
    for (int fj = 0; fj < 4; fj++) acc[fi][fj] = (f32x4){0.f, 0.f, 0.f, 0.f};

#pragma unroll 2
  for (int ks = 0; ks < DM/32; ks++) {
    bf16x8 af[4], bf[4];
#pragma unroll
    for (int fi = 0; fi < 4; fi++)
      af[fi] = *(const bf16x8*)(Am + (size_t)(mB + fi*16 + li)*DM + ks*32 + g*8);
#pragma unroll
    for (int fj = 0; fj < 4; fj++)
      bf[fj] = *(const bf16x8*)(Bn + (size_t)(nB + fj*16 + li)*DM + ks*32 + g*8);
#pragma unroll
    for (int fi = 0; fi < 4; fi++)
#pragma unroll
      for (int fj = 0; fj < 4; fj++)
        acc[fi][fj] = __builtin_amdgcn_mfma_f32_16x16x32_bf16(af[fi], bf[fj], acc[fi][fj], 0, 0, 0);
  }

  if (pj < 2) {
    unsigned short* dst = (pj == 0) ? Qo : Ko;
#pragma unroll
    for (int fi = 0; fi < 4; fi++) {
      int o0 = mB + fi*16 + g*4;
      float4 bb = *(const float4*)(bias + o0);
      int d0 = o0 & 127;
#pragma unroll
      for (int fj = 0; fj < 4; fj++) {
        int tok = nB + fj*16 + li;
        int bb_ = tok >> 11, n = tok & 2047;
        ushort4 v4;
        v4.x = f2bf(acc[fi][fj][0] + bb.x);
        v4.y = f2bf(acc[fi][fj][1] + bb.y);
        v4.z = f2bf(acc[fi][fj][2] + bb.z);
        v4.w = f2bf(acc[fi][fj][3] + bb.w);
        *(ushort4*)(dst + ((size_t)(bb_*NH + h)*NSEQ + n)*DK + d0) = v4;
      }
    }
  } else {
#pragma unroll
    for (int fj = 0; fj < 4; fj++) {
      int o  = nB + fj*16 + li;
      float bb = bias[o];
      int d  = o & 127;
#pragma unroll
      for (int fi = 0; fi < 4; fi++) {
        int tok0 = mB + fi*16 + g*4;
        int bb_ = tok0 >> 11, n0 = tok0 & 2047;
        ushort4 v4;
        v4.x = __builtin_bit_cast(unsigned short, (_Float16)(acc[fi][fj][0] + bb));
        v4.y = __builtin_bit_cast(unsigned short, (_Float16)(acc[fi][fj][1] + bb));
        v4.z = __builtin_bit_cast(unsigned short, (_Float16)(acc[fi][fj][2] + bb));
        v4.w = __builtin_bit_cast(unsigned short, (_Float16)(acc[fi][fj][3] + bb));
        *(ushort4*)(VTo + ((size_t)(bb_*NH + h)*DK + d)*NSEQ + n0) = v4;
      }
    }
  }
}

// ---------------------------------------------------------------- entmax helpers
__device__ __forceinline__ void scan16(const h2v* zh, float tau,
                                       float& f, float& g, float& c) {
  float ff = 0.f, gg = 0.f, cc = 0.f;
#if HAVE_FDOT2
  _Float16 th = (_Float16)tau;
  h2v t2 = {th, th};
  h2v zero2 = {(_Float16)0.f, (_Float16)0.f};
  h2v one2  = {(_Float16)1.f, (_Float16)1.f};
  h2v big2  = {(_Float16)60000.f, (_Float16)60000.f};
#pragma unroll
  for (int i = 0; i < 16; i++) {
    h2v d = __builtin_elementwise_max(zh[i] - t2, zero2);
    ff = __builtin_amdgcn_fdot2(d, d, ff, false);
    gg = __builtin_amdgcn_fdot2(d, one2, gg, false);
    h2v mm = __builtin_elementwise_min(d * big2, one2);
    cc = __builtin_amdgcn_fdot2(mm, one2, cc, false);
  }
#else
#pragma unroll
  for (int i = 0; i < 16; i++) {
#pragma unroll
    for (int j = 0; j < 2; j++) {
      float z = (float)zh[i][j];
      float d = fmaxf(z - tau, 0.f);
      ff = fmaf(d, d, ff);
      gg += d;
      cc += (d > 0.f) ? 1.f : 0.f;
    }
  }
#endif
  f = ff; g = gg; c = cc;
}

// frozen-support exact solve (Michelot step); Newton-back if overshot
__device__ __forceinline__ float nstep(float tau, float f, float g, float c, float m) {
  float num  = f - 1.0f;
  float disc = fmaxf(g*g - c*num, 0.f);
  float den  = (num >= 0.f) ? (g + sqrtf(disc)) : (2.0f * g);
  float t = tau + num / fmaxf(den, 1e-12f);
  return fminf(t, m - 0.01f);    // tau* <= m - 1/sqrt(2048); keeps support >= 1
}

// ---------------------------------------------------------------- fused attention
// Block = 32 q-rows of one (b,h); 512 thr = 8 waves; grid 384 (all resident,
// 2 blocks/CU via 66 KB LDS; launch_bounds(512,4) caps VGPR at 128 >= 68
// observed -> 16 waves/CU). Halves K/V L2 traffic vs QT=16 (768 -> 384 MB).
// Pipeline = R16's verified 2-buffer depth-1 counted-vmcnt + barrier pairs;
// sub stays 16 KB (2 gll/thread across 8 waves -> steady vmcnt(2)).
// Phase-1 wave role: (qh = w>>2 q-half, wk4 = w&3 k-tile); per-wave state
// unchanged from R16 (zr 64 VGPR, 4 q-rows/wave). Phase-3: (qh2 = w&1,
// dv = w>>1 -> d0 = dv*32). NOTE (R14/R17): never drop the s_barrier between
// vmcnt wait and LDS read of gll-staged data.
__global__ __launch_bounds__(512, 4) void attn_k(const unsigned short* __restrict__ Qb,
    const unsigned short* __restrict__ Kb, const _Float16* __restrict__ VTb,
    float* __restrict__ AO) {
  __shared__ _Float16 stg[2][8192];       // 2 x 16 KB staging
  __shared__ _Float16 zbuf[QT * ZP];      // 33.3 KB z / P tile

  int tid = threadIdx.x, lane = tid & 63, w = tid >> 6;   // w 0..7
  int g = lane >> 4, li = lane & 15;
  // bijective XCD swizzle: 384 blocks = 8 XCDs x 48 contiguous
  int swz = (blockIdx.x & 7) * 48 + (blockIdx.x >> 3);
  int bh = swz / (NSEQ/QT), qb = swz % (NSEQ/QT);         // NSEQ/QT = 64
  int qbase = qb * QT;
  int qh = w >> 2, wk4 = w & 3;                           // phase-1 roles
  const unsigned short* Qh  = Qb  + (size_t)bh * NSEQ * DK;
  const unsigned short* Kh  = Kb  + (size_t)bh * NSEQ * DK;
  const _Float16*       VTh = VTb + (size_t)bh * DK * NSEQ;
  const float zs = 0.044194173824159216f;   // 0.5 / sqrt(128)

  // Q B-frags for own q-half: cols q = qbase + qh*16 + li (persistent)
  bf16x8 bq[4];
#pragma unroll
  for (int ks = 0; ks < 4; ks++)
    bq[ks] = *(const bf16x8*)(Qh + (size_t)(qbase + qh*16 + li)*DK + ks*32 + g*8);
  // drain Q loads so vmcnt counting below is exact
  asm volatile("s_waitcnt vmcnt(0)" ::: "memory");
  __builtin_amdgcn_sched_barrier(0);

  // ---- cross-wave staging (16 KB sub = 2 gll issues per thread, 8 waves) ----
  // K sub: 64 k-rows x 128 halves, row-major, source chunk pre-swizzled.
  auto stageK = [&](int c, int s, int b) {
#pragma unroll
    for (int j = 0; j < 2; j++) {
      int idx   = (j*8 + w)*64 + lane;          // 16B-chunk index 0..1023
      int row_l = idx >> 4;                     // 0..63
      int ch    = idx & 15;
      const unsigned short* src = Kh + (size_t)(c*512 + s*64 + row_l)*DK
                                     + ((ch ^ (row_l & 7)) * 8);
      gll16(src, (void*)((char*)&stg[b][0] + (size_t)(j*8 + w) * 1024));
    }
  };
  // V sub: 128 d-rows x 64 halves (k), row-major, source chunk pre-swizzled.
  auto stageV = [&](int c, int s, int b) {
#pragma unroll
    for (int j = 0; j < 2; j++) {
      int idx = (j*8 + w)*64 + lane;            // 16B-chunk index 0..1023
      int dr  = idx >> 3;                       // 0..127
      int ch  = idx & 7;
      const _Float16* src = VTh + (size_t)dr*NSEQ + c*512 + s*64
                                + ((ch ^ (dr & 7)) * 8);
      gll16(src, (void*)((char*)&stg[b][0] + (size_t)(j*8 + w) * 1024));
    }
  };

  // ---- Phase 1: QK^T, 4 chunks of 512 k, each as 8 staged subs of 64 rows.
  // Swapped operands (A = K rows, B = Q cols): wave handles k-tile wk4 of the
  // sub x its q-half. D row = k, col = q -> h4 store into zbuf[q][k-in-chunk].
  h8 zr[4][4];   // [row r][chunk c]; wave w owns q rows w*4..w*4+3 (32 total)
  stageK(0, 0, 0);
#pragma unroll
  for (int c = 0; c < 4; c++) {
#pragma unroll
    for (int s = 0; s < 8; s++) {
      if (s < 7) stageK(c, s + 1, (s + 1) & 1);  // WAR safe per bottom-barrier(s-1)
      if (s < 7) asm volatile("s_waitcnt vmcnt(2)" ::: "memory");
      else       asm volatile("s_waitcnt vmcnt(0)" ::: "memory");
      __builtin_amdgcn_sched_barrier(0);
      __builtin_amdgcn_s_barrier();             // all waves: sub s landed
      __builtin_amdgcn_sched_barrier(0);
      const _Float16* kb = &stg[s & 1][0];
      bf16x8 bk[4];
#pragma unroll
      for (int ks = 0; ks < 4; ks++)
        bk[ks] = *(const bf16x8*)(kb + (size_t)(wk4*16 + li)*128
                                     + (((ks*4 + g) ^ (li & 7)) * 8));
      f32x4 za = (f32x4){0.f,0.f,0.f,0.f};
#pragma unroll
      for (int ks = 0; ks < 4; ks++)
        za = __builtin_amdgcn_mfma_f32_16x16x32_bf16(bk[ks], bq[ks], za, 0, 0, 0);
      h4 p;
#pragma unroll
      for (int r = 0; r < 4; r++) p[r] = (_Float16)(za[r] * zs);
      *(h4*)(zbuf + (size_t)(qh*16 + li)*ZP + s*64 + wk4*16 + g*4) = p;
      __builtin_amdgcn_sched_barrier(0);
      __builtin_amdgcn_s_barrier();             // all waves done reading sub s
      __builtin_amdgcn_sched_barrier(0);
    }
    if (c < 3) stageK(c+1, 0, 0);               // latency overlaps boundary drain
    __syncthreads();                            // z visible (full drain)
#pragma unroll
    for (int r = 0; r < 4; r++)
      zr[r][c] = *(const h8*)(zbuf + (size_t)(w*4 + r)*ZP + lane*8);
    __syncthreads();                            // zr reads done; zbuf reusable
  }

  // ---- Phase 2: wave-local Newton on rows w*4..w*4+3 (no LDS, no barriers)
  stageV(0, 0, 0);                              // prefetch V sub 0 under Newton
  float tau[4], mx[4];
#pragma unroll
  for (int r = 0; r < 4; r++) {
    union { h8 v[4]; h2v h[16]; } u;
#pragma unroll
    for (int c = 0; c < 4; c++) u.v[c] = zr[r][c];
    h2v m2 = u.h[0];
#pragma unroll
    for (int i = 1; i < 16; i++) m2 = __builtin_elementwise_max(m2, u.h[i]);
    float m = fmaxf((float)m2[0], (float)m2[1]);
#pragma unroll
    for (int off = 32; off > 0; off >>= 1) m = fmaxf(m, __shfl_xor(m, off));
    mx[r] = m;
    tau[r] = m - 1.0f;
  }
  for (int it = 0; it < NEWTON_IT; ++it) {
    float f[4], gg[4], cc[4];
#pragma unroll
    for (int r = 0; r < 4; r++) {
      union { h8 v[4]; h2v h[16]; } ur;
#pragma unroll
      for (int c = 0; c < 4; c++) ur.v[c] = zr[r][c];
      scan16(ur.h, tau[r], f[r], gg[r], cc[r]);
    }
#pragma unroll
    for (int off = 32; off > 0; off >>= 1) {
#pragma unroll
      for (int r = 0; r < 4; r++) {
        f[r]  += __shfl_xor(f[r],  off);
        gg[r] += __shfl_xor(gg[r], off);
        cc[r] += __shfl_xor(cc[r], off);
      }
    }
#pragma unroll
    for (int r = 0; r < 4; r++) tau[r] = nstep(tau[r], f[r], gg[r], cc[r], mx[r]);
  }

  // ---- Phase 3: PV, 4 chunks; P rebuilt into zbuf; V staged in 8 subs/chunk
  // with the same 2-buffer depth-1 counted-vmcnt pipeline.
  int qh2 = w & 1, dv = w >> 1;                 // phase-3 roles; d0 = dv*32
  int d0 = dv * 32;
  f32x4 pacc[2];
  pacc[0] = (f32x4){0.f,0.f,0.f,0.f};
  pacc[1] = (f32x4){0.f,0.f,0.f,0.f};
#pragma unroll
  for (int c = 0; c < 4; c++) {
    // P = relu(z - tau)^2 for own rows -> zbuf (full 512-k chunk)
#pragma unroll
    for (int r = 0; r < 4; r++) {
      union { h8 v; h2v h[4]; } u;
      u.v = zr[r][c];
      _Float16 th = (_Float16)tau[r];
      h2v t2 = {th, th};
      h2v zero2 = {(_Float16)0.f, (_Float16)0.f};
#pragma unroll
      for (int j = 0; j < 4; j++) {
        h2v d = __builtin_elementwise_max(u.h[j] - t2, zero2);
        u.h[j] = d * d;
      }
      *(h8*)(zbuf + (size_t)(w*4 + r)*ZP + lane*8) = u.v;
    }
    __syncthreads();                            // P visible (drains prologue gll)
#pragma unroll
    for (int s = 0; s < 8; s++) {
      if (s < 7) stageV(c, s + 1, (s + 1) & 1);  // WAR safe per bottom-barrier(s-1)
      if (s < 7) asm volatile("s_waitcnt vmcnt(2)" ::: "memory");
      else       asm volatile("s_waitcnt vmcnt(0)" ::: "memory");
      __builtin_amdgcn_sched_barrier(0);
      __builtin_amdgcn_s_barrier();             // all waves: V sub s landed
      __builtin_amdgcn_sched_barrier(0);
      const _Float16* vb = &stg[s & 1][0];
#pragma unroll
      for (int k2 = 0; k2 < 2; k2++) {
        h8 pa = *(const h8*)(zbuf + (size_t)(qh2*16 + li)*ZP + s*64 + k2*32 + g*8);
#pragma unroll
        for (int dt = 0; dt < 2; dt++) {
          int dr = d0 + dt*16 + li;             // d-row 0..127
          h8 bv = *(const h8*)(vb + (size_t)dr*64 + (((k2*4 + g) ^ (dr & 7)) * 8));
          pacc[dt] = __builtin_amdgcn_mfma_f32_16x16x32_f16(pa, bv, pacc[dt], 0, 0, 0);
        }
      }
      __builtin_amdgcn_sched_barrier(0);
      __builtin_amdgcn_s_barrier();             // all waves done reading V sub s
      __builtin_amdgcn_sched_barrier(0);
    }
    // next chunk's first V sub; buf0 reads finished (bottom barriers)
    if (c < 3) stageV(c+1, 0, 0);
    __syncthreads();                            // pa reads done before next P store
  }

  // ---- epilogue: out rows q = qbase + qh2*16 + g*4 + r, col d = d0 + dt*16 + li
  int b = bh / NH, h = bh % NH;
#pragma unroll
  for (int dt = 0; dt < 2; dt++)
#pragma unroll
    for (int r = 0; r < 4; r++)
      AO[((size_t)b*NSEQ + qbase + qh2*16 + g*4 + r)*DM + h*DK + d0 + dt*16 + li]
        = pacc[dt][r];
}

// ---------------------------------------------------------------- LN + residual
__global__ __launch_bounds__(256) void ln_k(const float* __restrict__ AO,
    const float* __restrict__ xT, const float* __restrict__ ga,
    const float* __restrict__ gb, float* __restrict__ outp) {
  int lane = threadIdx.x & 63;
  int wave = threadIdx.x >> 6;
  int row  = blockIdx.x * 4 + wave;
  const float* ao = AO + (size_t)row*DM;
  float2 c0 = *(const float2*)(ao + lane*2);
  float2 c1 = *(const float2*)(ao + 128 + lane*2);
  float2 c2 = *(const float2*)(ao + 256 + lane*2);
  float s  = c0.x + c0.y + c1.x + c1.y + c2.x + c2.y;
  float ss = c0.x*c0.x + c0.y*c0.y + c1.x*c1.x + c1.y*c1.y + c2.x*c2.x + c2.y*c2.y;
#pragma unroll
  for (int off = 32; off > 0; off >>= 1) {
    s  += __shfl_xor(s,  off);
    ss += __shfl_xor(ss, off);
  }
  float mean = s * (1.0f / 384.0f);
  float var  = (ss - 384.0f*mean*mean) * (1.0f / 383.0f);   // Bessel (n-1)
  var = fmaxf(var, 0.f);
  float inv = 1.0f / (sqrtf(var) + 1e-6f);                  // eps added to STD
  const float* xr = xT + (size_t)row*DM;
  float* op = outp + (size_t)row*DM;
#pragma unroll
  for (int ch = 0; ch < 3; ch++) {
    int i0 = ch*128 + lane*2;
    float2 g  = *(const float2*)(ga + i0);
    float2 bb = *(const float2*)(gb + i0);
    float2 xv = *(const float2*)(xr + i0);
    float2 av = (ch == 0) ? c0 : (ch == 1) ? c1 : c2;
    float2 o;
    o.x = g.x*(av.x - mean)*inv + bb.x + xv.x;
    o.y = g.y*(av.y - mean)*inv + bb.y + xv.y;
    *(float2*)(op + i0) = o;
  }
}

// ---------------------------------------------------------------- launch
extern "C" void kernel_launch(void* const* d_in, const int* in_sizes, int n_in,
                              void* d_out, int out_size, void* d_ws, size_t ws_size,
                              hipStream_t stream) {
  const float* x  = (const float*)d_in[0];
  const float* wq = (const float*)d_in[1];
  const float* bq = (const float*)d_in[2];
  const float* wk = (const float*)d_in[3];
  const float* bk = (const float*)d_in[4];
  const float* wv = (const float*)d_in[5];
  const float* bv = (const float*)d_in[6];
  const float* la = (const float*)d_in[7];
  const float* lb = (const float*)d_in[8];
  float* out = (float*)d_out;

  // ws: xT f32 | AO f32 | Qb bf16 | Kb bf16 | VT f16 | xbf bf16 | wbf bf16
  char* wsb = (char*)d_ws;
  float* xT = (float*)wsb;
  float* AO = (float*)(wsb + (size_t)SEG*4);
  unsigned short* Qb  = (unsigned short*)(wsb + (size_t)SEG*8);
  unsigned short* Kb  = (unsigned short*)(wsb + (size_t)SEG*8 + (size_t)SEG*2);
  unsigned short* VT  = (unsigned short*)(wsb + (size_t)SEG*8 + (size_t)SEG*4);
  unsigned short* xbf = (unsigned short*)(wsb + (size_t)SEG*8 + (size_t)SEG*6);
  unsigned short* wbf = (unsigned short*)(wsb + (size_t)SEG*8 + (size_t)SEG*8);

  hipLaunchKernelGGL(transpose_k, dim3(NSEQ/32, DM/32, BATCH), dim3(256), 0, stream,
                     x, xT, xbf);
  hipLaunchKernelGGL(wconv_k, dim3(DM*DM/1024, 3), dim3(256), 0, stream, wq, wk, wv, wbf);
  hipLaunchKernelGGL(proj_mfma_k, dim3(NTOK/128, NH, 3), dim3(256), 0, stream,
                     xbf, wbf, bq, bk, bv, Qb, Kb, VT);
  hipLaunchKernelGGL(attn_k, dim3(BATCH*NH*(NSEQ/QT)), dim3(512), 0, stream,
                     Qb, Kb, (const _Float16*)VT, AO);
  hipLaunchKernelGGL(ln_k, dim3(BATCH*NSEQ/4), dim3(256), 0, stream, AO, xT, la, lb, out);
}

// Round 20
// 110.689 us; speedup vs baseline: 1.0862x; 1.0862x over previous
//
#include <hip/hip_runtime.h>
#include <hip/hip_fp16.h>
#include <math.h>

// HieraFormer fused block (R16 structure = best known, + zbuf bank-spread ZP=524
// and NEWTON_IT=5):
//   transpose -> MFMA QKV proj -> fused attn (cross-wave global_load_lds
//   staging, 2-buffer depth-1 raw-barrier counted-vmcnt pipeline,
//   swapped-MFMA QK^T -> reg-resident fp16 z -> wave-local quadratic Newton
//   -> MFMA PV) -> LN+residual.
// B=2, D_MODEL=384, H=3, D_K=128, N=2048.
#define DM   384
#define NH   3
#define DK   128
#define NSEQ 2048
#define BATCH 2
#define NTOK (BATCH*NSEQ)      // 4096
#define SEG  (BATCH*NSEQ*DM)   // 1572864 elements
#define NEWTON_IT 5
#define QT   16                // q-rows per block
#define ZP   524               // z LDS pitch in halves (512+12): row stride 262
                               // words = 6 mod 32 banks -> spreads P3 row-reads
                               // across 16 banks (was 8-aliasing at 520)

typedef __attribute__((ext_vector_type(8))) short     bf16x8;
typedef __attribute__((ext_vector_type(4))) float     f32x4;
typedef __attribute__((ext_vector_type(8))) _Float16  h8;
typedef __attribute__((ext_vector_type(4))) _Float16  h4;
typedef __attribute__((ext_vector_type(2))) _Float16  h2v;

#if __has_builtin(__builtin_amdgcn_fdot2)
#define HAVE_FDOT2 1
#else
#define HAVE_FDOT2 0
#endif

// global -> LDS async DMA, 16B/lane. Global src per-lane; LDS dest wave-uniform
// (HW adds lane*16).
typedef const unsigned int __attribute__((address_space(1)))* gas1_t;
typedef unsigned int __attribute__((address_space(3)))* las3_t;
__device__ __forceinline__ void gll16(const void* g, void* l) {
  __builtin_amdgcn_global_load_lds((gas1_t)g, (las3_t)l, 16, 0, 0);
}

__device__ __forceinline__ unsigned short f2bf(float f) {
  unsigned u = __builtin_bit_cast(unsigned, f);
  u += 0x7FFFu + ((u >> 16) & 1u);          // RNE
  return (unsigned short)(u >> 16);
}

// ---------------------------------------------------------------- transpose
__global__ __launch_bounds__(256) void transpose_k(const float* __restrict__ x,
                                                   float* __restrict__ xT,
                                                   unsigned short* __restrict__ xbf) {
  __shared__ float tile[32][33];
  int b  = blockIdx.z;
  int cB = blockIdx.y * 32;
  int nB = blockIdx.x * 32;
  int tx = threadIdx.x & 31, ty = threadIdx.x >> 5;
#pragma unroll
  for (int i = 0; i < 4; i++)
    tile[ty + i*8][tx] = x[((size_t)b*DM + cB + ty + i*8)*NSEQ + nB + tx];
  __syncthreads();
#pragma unroll
  for (int i = 0; i < 4; i++) {
    float v = tile[tx][ty + i*8];
    size_t row = (size_t)b*NSEQ + nB + ty + i*8;
    xT [row*DM + cB + tx] = v;
    xbf[row*DM + cB + tx] = f2bf(v);
  }
}

// ---------------------------------------------------------------- weight convert
__global__ __launch_bounds__(256) void wconv_k(const float* __restrict__ wq,
    const float* __restrict__ wk, const float* __restrict__ wv,
    unsigned short* __restrict__ wbf) {
  int pj = blockIdx.y;
  const float* src = (pj == 0) ? wq : (pj == 1) ? wk : wv;
  int i = (blockIdx.x * 256 + threadIdx.x) * 4;
  float4 v = *(const float4*)(src + i);
  ushort4 o;
  o.x = f2bf(v.x); o.y = f2bf(v.y); o.z = f2bf(v.z); o.w = f2bf(v.w);
  *(ushort4*)(wbf + (size_t)pj*DM*DM + i) = o;
}

// ---------------------------------------------------------------- MFMA projections
// Q,K -> bf16 [b][h][n][d];  V -> fp16 transposed VT [b][h][d][n].
__global__ __launch_bounds__(256) void proj_mfma_k(
    const unsigned short* __restrict__ xbf,   // [NTOK][DM]
    const unsigned short* __restrict__ wbf,   // [3][DM][DM]
    const float* __restrict__ bq, const float* __restrict__ bk, const float* __restrict__ bv,
    unsigned short* __restrict__ Qo, unsigned short* __restrict__ Ko,
    unsigned short* __restrict__ VTo) {      // VT stored as f16 bit-pattern
  int tid = threadIdx.x, lane = tid & 63, w = tid >> 6;
  int g = lane >> 4, li = lane & 15;
  int wr = w >> 1, wc = w & 1;
  int h  = blockIdx.y;
  int pj = blockIdx.z;
  const unsigned short* wp0 = wbf + (size_t)pj * DM * DM;
  const float* bias = (pj == 0) ? bq : (pj == 1) ? bk : bv;

  const unsigned short *Am, *Bn;
  int mB, nB;
  if (pj < 2) { Am = wp0; mB = h*128 + wr*64;          Bn = xbf; nB = blockIdx.x*128 + wc*64; }
  else        { Am = xbf; mB = blockIdx.x*128 + wr*64; Bn = wp0; nB = h*128 + wc*64; }

  f32x4 acc[4][4];
#pragma unroll
  for (int fi = 0; fi < 4; fi++)
#pragma unroll
    for (int fj = 0; fj < 4; fj++) acc[fi][fj] = (f32x4){0.f, 0.f, 0.f, 0.f};

#pragma unroll 2
  for (int ks = 0; ks < DM/32; ks++) {
    bf16x8 af[4], bf[4];
#pragma unroll
    for (int fi = 0; fi < 4; fi++)
      af[fi] = *(const bf16x8*)(Am + (size_t)(mB + fi*16 + li)*DM + ks*32 + g*8);
#pragma unroll
    for (int fj = 0; fj < 4; fj++)
      bf[fj] = *(const bf16x8*)(Bn + (size_t)(nB + fj*16 + li)*DM + ks*32 + g*8);
#pragma unroll
    for (int fi = 0; fi < 4; fi++)
#pragma unroll
      for (int fj = 0; fj < 4; fj++)
        acc[fi][fj] = __builtin_amdgcn_mfma_f32_16x16x32_bf16(af[fi], bf[fj], acc[fi][fj], 0, 0, 0);
  }

  if (pj < 2) {
    unsigned short* dst = (pj == 0) ? Qo : Ko;
#pragma unroll
    for (int fi = 0; fi < 4; fi++) {
      int o0 = mB + fi*16 + g*4;
      float4 bb = *(const float4*)(bias + o0);
      int d0 = o0 & 127;
#pragma unroll
      for (int fj = 0; fj < 4; fj++) {
        int tok = nB + fj*16 + li;
        int bb_ = tok >> 11, n = tok & 2047;
        ushort4 v4;
        v4.x = f2bf(acc[fi][fj][0] + bb.x);
        v4.y = f2bf(acc[fi][fj][1] + bb.y);
        v4.z = f2bf(acc[fi][fj][2] + bb.z);
        v4.w = f2bf(acc[fi][fj][3] + bb.w);
        *(ushort4*)(dst + ((size_t)(bb_*NH + h)*NSEQ + n)*DK + d0) = v4;
      }
    }
  } else {
#pragma unroll
    for (int fj = 0; fj < 4; fj++) {
      int o  = nB + fj*16 + li;
      float bb = bias[o];
      int d  = o & 127;
#pragma unroll
      for (int fi = 0; fi < 4; fi++) {
        int tok0 = mB + fi*16 + g*4;
        int bb_ = tok0 >> 11, n0 = tok0 & 2047;
        ushort4 v4;
        v4.x = __builtin_bit_cast(unsigned short, (_Float16)(acc[fi][fj][0] + bb));
        v4.y = __builtin_bit_cast(unsigned short, (_Float16)(acc[fi][fj][1] + bb));
        v4.z = __builtin_bit_cast(unsigned short, (_Float16)(acc[fi][fj][2] + bb));
        v4.w = __builtin_bit_cast(unsigned short, (_Float16)(acc[fi][fj][3] + bb));
        *(ushort4*)(VTo + ((size_t)(bb_*NH + h)*DK + d)*NSEQ + n0) = v4;
      }
    }
  }
}

// ---------------------------------------------------------------- entmax helpers
__device__ __forceinline__ void scan16(const h2v* zh, float tau,
                                       float& f, float& g, float& c) {
  float ff = 0.f, gg = 0.f, cc = 0.f;
#if HAVE_FDOT2
  _Float16 th = (_Float16)tau;
  h2v t2 = {th, th};
  h2v zero2 = {(_Float16)0.f, (_Float16)0.f};
  h2v one2  = {(_Float16)1.f, (_Float16)1.f};
  h2v big2  = {(_Float16)60000.f, (_Float16)60000.f};
#pragma unroll
  for (int i = 0; i < 16; i++) {
    h2v d = __builtin_elementwise_max(zh[i] - t2, zero2);
    ff = __builtin_amdgcn_fdot2(d, d, ff, false);
    gg = __builtin_amdgcn_fdot2(d, one2, gg, false);
    h2v mm = __builtin_elementwise_min(d * big2, one2);
    cc = __builtin_amdgcn_fdot2(mm, one2, cc, false);
  }
#else
#pragma unroll
  for (int i = 0; i < 16; i++) {
#pragma unroll
    for (int j = 0; j < 2; j++) {
      float z = (float)zh[i][j];
      float d = fmaxf(z - tau, 0.f);
      ff = fmaf(d, d, ff);
      gg += d;
      cc += (d > 0.f) ? 1.f : 0.f;
    }
  }
#endif
  f = ff; g = gg; c = cc;
}

// frozen-support exact solve (Michelot step); Newton-back if overshot
__device__ __forceinline__ float nstep(float tau, float f, float g, float c, float m) {
  float num  = f - 1.0f;
  float disc = fmaxf(g*g - c*num, 0.f);
  float den  = (num >= 0.f) ? (g + sqrtf(disc)) : (2.0f * g);
  float t = tau + num / fmaxf(den, 1e-12f);
  return fminf(t, m - 0.01f);    // tau* <= m - 1/sqrt(2048); keeps support >= 1
}

// ---------------------------------------------------------------- fused attention
// Block = 16 q-rows of one (b,h); 256 thr = 4 waves; grid 768 = 3 blocks/CU.
// R16's verified pipeline: 2 staging buffers, prefetch depth 1, counted
// s_waitcnt vmcnt(4) (never 0 in steady state) + raw s_barrier pairs per sub.
// NOTE (R14/R17 lesson): counted-vmcnt gll consumption WITHOUT an s_barrier
// between wait and LDS read fails on this HW/compiler -- do not remove it.
__global__ __launch_bounds__(256, 3) void attn_k(const unsigned short* __restrict__ Qb,
    const unsigned short* __restrict__ Kb, const _Float16* __restrict__ VTb,
    float* __restrict__ AO) {
  __shared__ _Float16 stg[2][8192];       // 2 x 16 KB staging
  __shared__ _Float16 zbuf[QT * ZP];      // 16.8 KB z / P tile

  int tid = threadIdx.x, lane = tid & 63, w = tid >> 6;   // w 0..3
  int g = lane >> 4, li = lane & 15;
  // bijective XCD swizzle: 768 blocks = 8 XCDs x 96 contiguous
  int swz = (blockIdx.x & 7) * 96 + (blockIdx.x >> 3);
  int bh = swz / (NSEQ/QT), qb = swz % (NSEQ/QT);         // NSEQ/QT = 128
  int qbase = qb * QT;
  const unsigned short* Qh  = Qb  + (size_t)bh * NSEQ * DK;
  const unsigned short* Kh  = Kb  + (size_t)bh * NSEQ * DK;
  const _Float16*       VTh = VTb + (size_t)bh * DK * NSEQ;
  const float zs = 0.044194173824159216f;   // 0.5 / sqrt(128)

  // Q B-frags: cols q = qbase + li, k-slice ks*32 + g*8 (persistent)
  bf16x8 bq[4];
#pragma unroll
  for (int ks = 0; ks < 4; ks++)
    bq[ks] = *(const bf16x8*)(Qh + (size_t)(qbase + li)*DK + ks*32 + g*8);
  // drain Q loads so vmcnt counting below is exact
  asm volatile("s_waitcnt vmcnt(0)" ::: "memory");
  __builtin_amdgcn_sched_barrier(0);

  // ---- cross-wave staging (16 KB sub = 4 gll issues per thread) ----
  // K sub: 64 k-rows x 128 halves, row-major, source chunk pre-swizzled.
  auto stageK = [&](int c, int s, int b) {
#pragma unroll
    for (int j = 0; j < 4; j++) {
      int idx   = (j*4 + w)*64 + lane;          // 16B-chunk index 0..1023
      int row_l = idx >> 4;                     // 0..63
      int ch    = idx & 15;
      const unsigned short* src = Kh + (size_t)(c*512 + s*64 + row_l)*DK
                                     + ((ch ^ (row_l & 7)) * 8);
      gll16(src, (void*)((char*)&stg[b][0] + (size_t)(j*4 + w) * 1024));
    }
  };
  // V sub: 128 d-rows x 64 halves (k), row-major, source chunk pre-swizzled.
  auto stageV = [&](int c, int s, int b) {
#pragma unroll
    for (int j = 0; j < 4; j++) {
      int idx = (j*4 + w)*64 + lane;            // 16B-chunk index 0..1023
      int dr  = idx >> 3;                       // 0..127
      int ch  = idx & 7;
      const _Float16* src = VTh + (size_t)dr*NSEQ + c*512 + s*64
                                + ((ch ^ (dr & 7)) * 8);
      gll16(src, (void*)((char*)&stg[b][0] + (size_t)(j*4 + w) * 1024));
    }
  };

  // ---- Phase 1: QK^T, 4 chunks of 512 k, each as 8 staged subs of 64 rows.
  // Swapped operands (A = K rows, B = Q cols): D row = k, col = q -> h4 store.
  h8 zr[4][4];   // [row r][chunk c]; wave w owns q rows w*4..w*4+3
  stageK(0, 0, 0);
#pragma unroll
  for (int c = 0; c < 4; c++) {
#pragma unroll
    for (int s = 0; s < 8; s++) {
      if (s < 7) stageK(c, s + 1, (s + 1) & 1);  // WAR safe: buf read done @ bottom-barrier(s-1)
      if (s < 7) asm volatile("s_waitcnt vmcnt(4)" ::: "memory");
      else       asm volatile("s_waitcnt vmcnt(0)" ::: "memory");
      __builtin_amdgcn_sched_barrier(0);
      __builtin_amdgcn_s_barrier();             // all waves: sub s landed
      __builtin_amdgcn_sched_barrier(0);
      const _Float16* kb = &stg[s & 1][0];
      bf16x8 bk[4];
#pragma unroll
      for (int ks = 0; ks < 4; ks++)
        bk[ks] = *(const bf16x8*)(kb + (size_t)(w*16 + li)*128
                                     + (((ks*4 + g) ^ (li & 7)) * 8));
      f32x4 za = (f32x4){0.f,0.f,0.f,0.f};
#pragma unroll
      for (int ks = 0; ks < 4; ks++)
        za = __builtin_amdgcn_mfma_f32_16x16x32_bf16(bk[ks], bq[ks], za, 0, 0, 0);
      h4 p;
#pragma unroll
      for (int r = 0; r < 4; r++) p[r] = (_Float16)(za[r] * zs);
      *(h4*)(zbuf + (size_t)li*ZP + s*64 + w*16 + g*4) = p;
      __builtin_amdgcn_sched_barrier(0);
      __builtin_amdgcn_s_barrier();             // all waves done reading sub s
      __builtin_amdgcn_sched_barrier(0);
    }
    if (c < 3) stageK(c+1, 0, 0);               // buf0 reads done per bottom barriers
    __syncthreads();                            // z visible (full drain)
#pragma unroll
    for (int r = 0; r < 4; r++)
      zr[r][c] = *(const h8*)(zbuf + (size_t)(w*4 + r)*ZP + lane*8);
    __syncthreads();                            // zr reads done; zbuf reusable
  }

  // ---- Phase 2: wave-local Newton on rows w*4..w*4+3 (no LDS, no barriers)
  // (phase 3's first V sub is prefetched before Newton to hide its latency)
  stageV(0, 0, 0);
  float tau[4], mx[4];
#pragma unroll
  for (int r = 0; r < 4; r++) {
    union { h8 v[4]; h2v h[16]; } u;
#pragma unroll
    for (int c = 0; c < 4; c++) u.v[c] = zr[r][c];
    h2v m2 = u.h[0];
#pragma unroll
    for (int i = 1; i < 16; i++) m2 = __builtin_elementwise_max(m2, u.h[i]);
    float m = fmaxf((float)m2[0], (float)m2[1]);
#pragma unroll
    for (int off = 32; off > 0; off >>= 1) m = fmaxf(m, __shfl_xor(m, off));
    mx[r] = m;
    tau[r] = m - 1.0f;
  }
  for (int it = 0; it < NEWTON_IT; ++it) {
    float f[4], gg[4], cc[4];
#pragma unroll
    for (int r = 0; r < 4; r++) {
      union { h8 v[4]; h2v h[16]; } ur;
#pragma unroll
      for (int c = 0; c < 4; c++) ur.v[c] = zr[r][c];
      scan16(ur.h, tau[r], f[r], gg[r], cc[r]);
    }
#pragma unroll
    for (int off = 32; off > 0; off >>= 1) {
#pragma unroll
      for (int r = 0; r < 4; r++) {
        f[r]  += __shfl_xor(f[r],  off);
        gg[r] += __shfl_xor(gg[r], off);
        cc[r] += __shfl_xor(cc[r], off);
      }
    }
#pragma unroll
    for (int r = 0; r < 4; r++) tau[r] = nstep(tau[r], f[r], gg[r], cc[r], mx[r]);
  }

  // ---- Phase 3: PV, 4 chunks; P rebuilt into zbuf; V staged in 8 subs/chunk
  // with the same 2-buffer depth-1 counted-vmcnt pipeline.
  f32x4 pacc[2];
  pacc[0] = (f32x4){0.f,0.f,0.f,0.f};
  pacc[1] = (f32x4){0.f,0.f,0.f,0.f};
#pragma unroll
  for (int c = 0; c < 4; c++) {
    // P = relu(z - tau)^2 for own rows -> zbuf (full 512-k chunk)
#pragma unroll
    for (int r = 0; r < 4; r++) {
      union { h8 v; h2v h[4]; } u;
      u.v = zr[r][c];
      _Float16 th = (_Float16)tau[r];
      h2v t2 = {th, th};
      h2v zero2 = {(_Float16)0.f, (_Float16)0.f};
#pragma unroll
      for (int j = 0; j < 4; j++) {
        h2v d = __builtin_elementwise_max(u.h[j] - t2, zero2);
        u.h[j] = d * d;
      }
      *(h8*)(zbuf + (size_t)(w*4 + r)*ZP + lane*8) = u.v;
    }
    __syncthreads();                            // P visible (drains prologue gll)
#pragma unroll
    for (int s = 0; s < 8; s++) {
      if (s < 7) stageV(c, s + 1, (s + 1) & 1);  // WAR safe per bottom-barrier(s-1)
      if (s < 7) asm volatile("s_waitcnt vmcnt(4)" ::: "memory");
      else       asm volatile("s_waitcnt vmcnt(0)" ::: "memory");
      __builtin_amdgcn_sched_barrier(0);
      __builtin_amdgcn_s_barrier();             // all waves: V sub s landed
      __builtin_amdgcn_sched_barrier(0);
      const _Float16* vb = &stg[s & 1][0];
#pragma unroll
      for (int k2 = 0; k2 < 2; k2++) {
        h8 pa = *(const h8*)(zbuf + (size_t)li*ZP + s*64 + k2*32 + g*8);
#pragma unroll
        for (int dt = 0; dt < 2; dt++) {
          int dr = w*32 + dt*16 + li;           // d-row 0..127
          h8 bv = *(const h8*)(vb + (size_t)dr*64 + (((k2*4 + g) ^ (dr & 7)) * 8));
          pacc[dt] = __builtin_amdgcn_mfma_f32_16x16x32_f16(pa, bv, pacc[dt], 0, 0, 0);
        }
      }
      __builtin_amdgcn_sched_barrier(0);
      __builtin_amdgcn_s_barrier();             // all waves done reading V sub s
      __builtin_amdgcn_sched_barrier(0);
    }
    // next chunk's first V sub; buf0 reads finished (bottom barriers)
    if (c < 3) stageV(c+1, 0, 0);
  }

  // ---- epilogue: out rows q = qbase + g*4 + r, col d = w*32 + dt*16 + li
  int b = bh / NH, h = bh % NH;
#pragma unroll
  for (int dt = 0; dt < 2; dt++)
#pragma unroll
    for (int r = 0; r < 4; r++)
      AO[((size_t)b*NSEQ + qbase + g*4 + r)*DM + h*DK + w*32 + dt*16 + li] = pacc[dt][r];
}

// ---------------------------------------------------------------- LN + residual
__global__ __launch_bounds__(256) void ln_k(const float* __restrict__ AO,
    const float* __restrict__ xT, const float* __restrict__ ga,
    const float* __restrict__ gb, float* __restrict__ outp) {
  int lane = threadIdx.x & 63;
  int wave = threadIdx.x >> 6;
  int row  = blockIdx.x * 4 + wave;
  const float* ao = AO + (size_t)row*DM;
  float2 c0 = *(const float2*)(ao + lane*2);
  float2 c1 = *(const float2*)(ao + 128 + lane*2);
  float2 c2 = *(const float2*)(ao + 256 + lane*2);
  float s  = c0.x + c0.y + c1.x + c1.y + c2.x + c2.y;
  float ss = c0.x*c0.x + c0.y*c0.y + c1.x*c1.x + c1.y*c1.y + c2.x*c2.x + c2.y*c2.y;
#pragma unroll
  for (int off = 32; off > 0; off >>= 1) {
    s  += __shfl_xor(s,  off);
    ss += __shfl_xor(ss, off);
  }
  float mean = s * (1.0f / 384.0f);
  float var  = (ss - 384.0f*mean*mean) * (1.0f / 383.0f);   // Bessel (n-1)
  var = fmaxf(var, 0.f);
  float inv = 1.0f / (sqrtf(var) + 1e-6f);                  // eps added to STD
  const float* xr = xT + (size_t)row*DM;
  float* op = outp + (size_t)row*DM;
#pragma unroll
  for (int ch = 0; ch < 3; ch++) {
    int i0 = ch*128 + lane*2;
    float2 g  = *(const float2*)(ga + i0);
    float2 bb = *(const float2*)(gb + i0);
    float2 xv = *(const float2*)(xr + i0);
    float2 av = (ch == 0) ? c0 : (ch == 1) ? c1 : c2;
    float2 o;
    o.x = g.x*(av.x - mean)*inv + bb.x + xv.x;
    o.y = g.y*(av.y - mean)*inv + bb.y + xv.y;
    *(float2*)(op + i0) = o;
  }
}

// ---------------------------------------------------------------- launch
extern "C" void kernel_launch(void* const* d_in, const int* in_sizes, int n_in,
                              void* d_out, int out_size, void* d_ws, size_t ws_size,
                              hipStream_t stream) {
  const float* x  = (const float*)d_in[0];
  const float* wq = (const float*)d_in[1];
  const float* bq = (const float*)d_in[2];
  const float* wk = (const float*)d_in[3];
  const float* bk = (const float*)d_in[4];
  const float* wv = (const float*)d_in[5];
  const float* bv = (const float*)d_in[6];
  const float* la = (const float*)d_in[7];
  const float* lb = (const float*)d_in[8];
  float* out = (float*)d_out;

  // ws: xT f32 | AO f32 | Qb bf16 | Kb bf16 | VT f16 | xbf bf16 | wbf bf16
  char* wsb = (char*)d_ws;
  float* xT = (float*)wsb;
  float* AO = (float*)(wsb + (size_t)SEG*4);
  unsigned short* Qb  = (unsigned short*)(wsb + (size_t)SEG*8);
  unsigned short* Kb  = (unsigned short*)(wsb + (size_t)SEG*8 + (size_t)SEG*2);
  unsigned short* VT  = (unsigned short*)(wsb + (size_t)SEG*8 + (size_t)SEG*4);
  unsigned short* xbf = (unsigned short*)(wsb + (size_t)SEG*8 + (size_t)SEG*6);
  unsigned short* wbf = (unsigned short*)(wsb + (size_t)SEG*8 + (size_t)SEG*8);

  hipLaunchKernelGGL(transpose_k, dim3(NSEQ/32, DM/32, BATCH), dim3(256), 0, stream,
                     x, xT, xbf);
  hipLaunchKernelGGL(wconv_k, dim3(DM*DM/1024, 3), dim3(256), 0, stream, wq, wk, wv, wbf);
  hipLaunchKernelGGL(proj_mfma_k, dim3(NTOK/128, NH, 3), dim3(256), 0, stream,
                     xbf, wbf, bq, bk, bv, Qb, Kb, VT);
  hipLaunchKernelGGL(attn_k, dim3(BATCH*NH*(NSEQ/QT)), dim3(256), 0, stream,
                     Qb, Kb, (const _Float16*)VT, AO);
  hipLaunchKernelGGL(ln_k, dim3(BATCH*NSEQ/4), dim3(256), 0, stream, AO, xT, la, lb, out);
}